// Round 4
// baseline (411.930 us; speedup 1.0000x reference)
//
#include <hip/hip_runtime.h>

#define B_TOT 8192
#define NN 64
#define FF 32
#define ITERS 48
#define THRESH 0.35f

// ws layout: [0..3] int Tmax (atomicMax target, memset to 0 each launch),
//            [16 .. 16 + B*48) unsigned char selection indices per batch.

// GREEDY KERNEL: byte-identical to the round-3 passing version (409us family).
// Its fp expression structure (rolled distance loop, serial dsum chain,
// 4-accumulator trees, gain accumulation order) reproduces the reference
// selection trajectory exactly -- do NOT restructure fp-bearing code here;
// unrolling the distance loop reassociates dsum and flips near-tie argmaxes
// (rounds 1-2 failed this way, bit-identically).
__global__ __launch_bounds__(64) void gat_greedy_kernel(
    const float* __restrict__ mail,
    const float* __restrict__ attn_w,
    const float* __restrict__ src_norm,
    int* __restrict__ tmax_ws,
    unsigned char* __restrict__ sels_ws)
{
    const int b = blockIdx.x;
    const int lane = threadIdx.x;

    // sims row stride 65: lane-varying reads sims[sel*65+lane] hit banks
    // (sel+lane)%32 -> 2-way aliasing only (free on CDNA4).
    __shared__ __align__(16) float sims[NN * 65];
    __shared__ __align__(16) float c_lds[NN];
    __shared__ float qarr[NN];
    __shared__ float sarr[NN];

    // ---- load own raw mail row into registers ----
    const float* __restrict__ myrow = mail + ((size_t)b * NN + lane) * FF;
    float a[FF];
#pragma unroll
    for (int k = 0; k < 8; ++k) {
        const float4 v = reinterpret_cast<const float4*>(myrow)[k];
        a[4*k+0] = v.x; a[4*k+1] = v.y; a[4*k+2] = v.z; a[4*k+3] = v.w;
    }
    const float sn = src_norm[b * NN + lane];

    // |a|^2 with the SAME 4-accumulator tree as the dot below (diag consistency)
    float q0 = 0.f, q1 = 0.f, q2 = 0.f, q3 = 0.f;
#pragma unroll
    for (int k = 0; k < 8; ++k) {
        q0 = fmaf(a[4*k+0], a[4*k+0], q0);
        q1 = fmaf(a[4*k+1], a[4*k+1], q1);
        q2 = fmaf(a[4*k+2], a[4*k+2], q2);
        q3 = fmaf(a[4*k+3], a[4*k+3], q3);
    }
    const float q = (q0 + q1) + (q2 + q3);

    // logits: (sigma_n * a_n) . w  computed as sigma_n * (a_n . w)
    float lg = 0.f;
#pragma unroll
    for (int f = 0; f < FF; ++f) lg = fmaf(a[f], attn_w[f], lg);
    lg *= sn;

    qarr[lane] = q;
    sarr[lane] = sn;
    __syncthreads();

    // ---- softmax over the 64 neighbors (wave butterfly) ----
    float mx = lg;
#pragma unroll
    for (int off = 32; off > 0; off >>= 1)
        mx = fmaxf(mx, __shfl_xor(mx, off, 64));
    const float ex = __expf(lg - mx);
    float se = ex;
#pragma unroll
    for (int off = 32; off > 0; off >>= 1)
        se += __shfl_xor(se, off, 64);
    const float attn = ex / se;

    // ---- pairwise distances: lane n computes row n via Gram trick.
    // Row m operand address is wave-uniform -> scalar (s_load) path.
    const float sqn = sn * sn * q;
    float dsum = 0.f;
    for (int m = 0; m < NN; ++m) {
        const float4* __restrict__ Am =
            reinterpret_cast<const float4*>(mail + ((size_t)b * NN + m) * FF);
        float g0 = 0.f, g1 = 0.f, g2 = 0.f, g3 = 0.f;
#pragma unroll
        for (int k = 0; k < 8; ++k) {
            const float4 v = Am[k];
            g0 = fmaf(a[4*k+0], v.x, g0);
            g1 = fmaf(a[4*k+1], v.y, g1);
            g2 = fmaf(a[4*k+2], v.z, g2);
            g3 = fmaf(a[4*k+3], v.w, g3);
        }
        const float g  = (g0 + g1) + (g2 + g3);
        const float sm = sarr[m];
        const float qm = qarr[m];
        const float sqm = sm * sm * qm;
        const float d2  = (sqn - 2.f * (sn * sm) * g) + sqm;
        const float d   = sqrtf(fmaxf(d2, 0.f));
        dsum += d;
        sims[lane * 65 + m] = d;   // stash distance; exp applied after mean known
    }

    // per-batch mean distance
    float tot = dsum;
#pragma unroll
    for (int off = 32; off > 0; off >>= 1)
        tot += __shfl_xor(tot, off, 64);
    const float meand = tot * (1.f / (float)(NN * NN));
    const float inv   = -1.f / meand;   // SIGMA = 1

    // sims = exp(-d/mean); keep a register copy of own row for the greedy loop
    float srow[NN];
#pragma unroll
    for (int m = 0; m < NN; ++m) {
        const float d = sims[lane * 65 + m];
        const float s = __expf(d * inv);
        srow[m] = s;
        sims[lane * 65 + m] = s;
    }
    // Pin srow into VGPRs (numerics-invariant; kept from round 3's passing build)
#pragma unroll
    for (int m = 0; m < NN; ++m)
        asm volatile("" : "+v"(srow[m]));

    c_lds[lane] = 0.f;
    float c_reg = 0.f;
    __syncthreads();

    // ---- greedy loop: all 48 iterations (global stop resolved later via Tmax) ----
    int firstBelow = ITERS;      // == T_b (prefix length with maxgain >= THRESH)
    bool seenBelow = false;

    for (int t = 0; t < ITERS; ++t) {
        // gain_n = attn_n * sum_m relu(s_nm - c_m)   (reference-accurate form)
        float gain = 0.f;
#pragma unroll
        for (int k = 0; k < 16; ++k) {
            const float4 cv = reinterpret_cast<const float4*>(c_lds)[k];  // uniform b128 broadcast
            gain += fmaxf(srow[4*k+0] - cv.x, 0.f);
            gain += fmaxf(srow[4*k+1] - cv.y, 0.f);
            gain += fmaxf(srow[4*k+2] - cv.z, 0.f);
            gain += fmaxf(srow[4*k+3] - cv.w, 0.f);
        }
        gain *= attn;

        // argmax with FIRST-index tie-break (matches jnp.argmax, incl. all-zero tail)
        float gv = gain; int gi = lane;
#pragma unroll
        for (int off = 32; off > 0; off >>= 1) {
            const float ov = __shfl_xor(gv, off, 64);
            const int   oi = __shfl_xor(gi, off, 64);
            if (ov > gv || (ov == gv && oi < gi)) { gv = ov; gi = oi; }
        }

        if (!seenBelow && gv < THRESH) { firstBelow = t; seenBelow = true; }
        if (lane == 0) sels_ws[(size_t)b * ITERS + t] = (unsigned char)gi;

        // cache update: lane m handles column m (conflict-free stride-65 read)
        const float srl = sims[gi * 65 + lane];
        c_reg = fmaxf(c_reg, srl);
        c_lds[lane] = c_reg;
        __syncthreads();   // single-wave block: cheap; guards LDS RAW ordering
    }

    if (lane == 0) atomicMax(tmax_ws, firstBelow);
}

// ACCUM KERNEL (rewritten, numerics bit-exact vs proven):
// old version: runtime-bound loop, each iter a dependent chain
// sel-byte load -> addr -> mail load -> fmaf (~48 x ~200cy latency links).
// new: preload all 48 sel bytes (3x uint4), fully unroll, issue every
// mail/src_norm load unconditionally (greedy always writes all 48 sels, so
// addresses are valid), and predicate only the WEIGHT: fmaf(m, t<C ? w : 0, acc).
// Terms beyond C add exactly +/-0 -> acc bit sequence identical to the proven
// serial accumulation. 256-thread blocks = 8 batches/block.
__global__ __launch_bounds__(256) void gat_accum_kernel(
    const float* __restrict__ mail,
    const float* __restrict__ src_norm,
    const float* __restrict__ dst_norm,
    const int* __restrict__ tmax_ws,
    const unsigned char* __restrict__ sels_ws,
    float* __restrict__ out)
{
    const int lane = threadIdx.x & 31;
    const int b = blockIdx.x * 8 + (threadIdx.x >> 5);
    // contributions happen for t = 0 .. min(47, Tmax)  (append-then-check)
    const int C = min(ITERS, *tmax_ws + 1);

    // preload all 48 selection bytes (16B-aligned: offset 16 + b*48)
    const uint4* __restrict__ sp =
        reinterpret_cast<const uint4*>(sels_ws + (size_t)b * ITERS);
    const uint4 s0 = sp[0], s1 = sp[1], s2 = sp[2];
    const unsigned sw[12] = { s0.x, s0.y, s0.z, s0.w,
                              s1.x, s1.y, s1.z, s1.w,
                              s2.x, s2.y, s2.z, s2.w };

    float acc = 0.f;
#pragma unroll
    for (int t = 0; t < ITERS; ++t) {
        const int sel = (int)((sw[t >> 2] >> ((t & 3) * 8)) & 0xFFu);
        const float mv = mail[((size_t)b * NN + sel) * FF + lane];
        const float wv = src_norm[b * NN + sel];
        acc = fmaf(mv, (t < C) ? wv : 0.f, acc);
    }
    out[b * FF + lane] = acc * dst_norm[b];
}

extern "C" void kernel_launch(void* const* d_in, const int* in_sizes, int n_in,
                              void* d_out, int out_size, void* d_ws, size_t ws_size,
                              hipStream_t stream)
{
    const float* mail     = (const float*)d_in[0];
    const float* attn_w   = (const float*)d_in[1];
    const float* src_norm = (const float*)d_in[2];
    const float* dst_norm = (const float*)d_in[3];
    float* out = (float*)d_out;

    int* tmax_ws = (int*)d_ws;
    unsigned char* sels_ws = (unsigned char*)d_ws + 16;

    hipMemsetAsync(d_ws, 0, 4, stream);   // zero the Tmax word (ws is re-poisoned 0xAA)
    gat_greedy_kernel<<<dim3(B_TOT), dim3(64), 0, stream>>>(
        mail, attn_w, src_norm, tmax_ws, sels_ws);
    gat_accum_kernel<<<dim3(B_TOT / 8), dim3(256), 0, stream>>>(
        mail, src_norm, dst_norm, tmax_ws, sels_ws, out);
}

// Round 5
// 374.557 us; speedup vs baseline: 1.0998x; 1.0998x over previous
//
#include <hip/hip_runtime.h>

#define B_TOT 8192
#define NN 64
#define FF 32
#define ITERS 48
#define THRESH 0.35f

// ws layout:
//   [0..3]                int Tmax (atomicMax target; memset to 0 each launch)
//   [16 .. 16+B*48)       unsigned char selections per batch (393232 total)
//   [524288 .. +2MB)      float attn[B][64]          (split path only)
//   [4194304 .. +134MB)   float sims_g[B][64][64]    (split path only)
#define ATTN_OFF  (524288)
#define SIMS_OFF  (4194304)
#define WS_NEEDED (SIMS_OFF + (size_t)B_TOT * NN * NN * 4)

// ---------------------------------------------------------------------------
// PROVEN MONOLITHIC KERNEL (fallback; byte-identical to the r3 passing build).
// Its compiled fp sequence reproduces the reference selection trajectory.
// Do NOT restructure fp-bearing code here.
// ---------------------------------------------------------------------------
__global__ __launch_bounds__(64) void gat_greedy_kernel(
    const float* __restrict__ mail,
    const float* __restrict__ attn_w,
    const float* __restrict__ src_norm,
    int* __restrict__ tmax_ws,
    unsigned char* __restrict__ sels_ws)
{
    const int b = blockIdx.x;
    const int lane = threadIdx.x;

    __shared__ __align__(16) float sims[NN * 65];
    __shared__ __align__(16) float c_lds[NN];
    __shared__ float qarr[NN];
    __shared__ float sarr[NN];

    const float* __restrict__ myrow = mail + ((size_t)b * NN + lane) * FF;
    float a[FF];
#pragma unroll
    for (int k = 0; k < 8; ++k) {
        const float4 v = reinterpret_cast<const float4*>(myrow)[k];
        a[4*k+0] = v.x; a[4*k+1] = v.y; a[4*k+2] = v.z; a[4*k+3] = v.w;
    }
    const float sn = src_norm[b * NN + lane];

    float q0 = 0.f, q1 = 0.f, q2 = 0.f, q3 = 0.f;
#pragma unroll
    for (int k = 0; k < 8; ++k) {
        q0 = fmaf(a[4*k+0], a[4*k+0], q0);
        q1 = fmaf(a[4*k+1], a[4*k+1], q1);
        q2 = fmaf(a[4*k+2], a[4*k+2], q2);
        q3 = fmaf(a[4*k+3], a[4*k+3], q3);
    }
    const float q = (q0 + q1) + (q2 + q3);

    float lg = 0.f;
#pragma unroll
    for (int f = 0; f < FF; ++f) lg = fmaf(a[f], attn_w[f], lg);
    lg *= sn;

    qarr[lane] = q;
    sarr[lane] = sn;
    __syncthreads();

    float mx = lg;
#pragma unroll
    for (int off = 32; off > 0; off >>= 1)
        mx = fmaxf(mx, __shfl_xor(mx, off, 64));
    const float ex = __expf(lg - mx);
    float se = ex;
#pragma unroll
    for (int off = 32; off > 0; off >>= 1)
        se += __shfl_xor(se, off, 64);
    const float attn = ex / se;

    const float sqn = sn * sn * q;
    float dsum = 0.f;
    for (int m = 0; m < NN; ++m) {
        const float4* __restrict__ Am =
            reinterpret_cast<const float4*>(mail + ((size_t)b * NN + m) * FF);
        float g0 = 0.f, g1 = 0.f, g2 = 0.f, g3 = 0.f;
#pragma unroll
        for (int k = 0; k < 8; ++k) {
            const float4 v = Am[k];
            g0 = fmaf(a[4*k+0], v.x, g0);
            g1 = fmaf(a[4*k+1], v.y, g1);
            g2 = fmaf(a[4*k+2], v.z, g2);
            g3 = fmaf(a[4*k+3], v.w, g3);
        }
        const float g  = (g0 + g1) + (g2 + g3);
        const float sm = sarr[m];
        const float qm = qarr[m];
        const float sqm = sm * sm * qm;
        const float d2  = (sqn - 2.f * (sn * sm) * g) + sqm;
        const float d   = sqrtf(fmaxf(d2, 0.f));
        dsum += d;
        sims[lane * 65 + m] = d;
    }

    float tot = dsum;
#pragma unroll
    for (int off = 32; off > 0; off >>= 1)
        tot += __shfl_xor(tot, off, 64);
    const float meand = tot * (1.f / (float)(NN * NN));
    const float inv   = -1.f / meand;   // SIGMA = 1

    float srow[NN];
#pragma unroll
    for (int m = 0; m < NN; ++m) {
        const float d = sims[lane * 65 + m];
        const float s = __expf(d * inv);
        srow[m] = s;
        sims[lane * 65 + m] = s;
    }
#pragma unroll
    for (int m = 0; m < NN; ++m)
        asm volatile("" : "+v"(srow[m]));

    c_lds[lane] = 0.f;
    float c_reg = 0.f;
    __syncthreads();

    int firstBelow = ITERS;
    bool seenBelow = false;

    for (int t = 0; t < ITERS; ++t) {
        float gain = 0.f;
#pragma unroll
        for (int k = 0; k < 16; ++k) {
            const float4 cv = reinterpret_cast<const float4*>(c_lds)[k];
            gain += fmaxf(srow[4*k+0] - cv.x, 0.f);
            gain += fmaxf(srow[4*k+1] - cv.y, 0.f);
            gain += fmaxf(srow[4*k+2] - cv.z, 0.f);
            gain += fmaxf(srow[4*k+3] - cv.w, 0.f);
        }
        gain *= attn;

        float gv = gain; int gi = lane;
#pragma unroll
        for (int off = 32; off > 0; off >>= 1) {
            const float ov = __shfl_xor(gv, off, 64);
            const int   oi = __shfl_xor(gi, off, 64);
            if (ov > gv || (ov == gv && oi < gi)) { gv = ov; gi = oi; }
        }

        if (!seenBelow && gv < THRESH) { firstBelow = t; seenBelow = true; }
        if (lane == 0) sels_ws[(size_t)b * ITERS + t] = (unsigned char)gi;

        const float srl = sims[gi * 65 + lane];
        c_reg = fmaxf(c_reg, srl);
        c_lds[lane] = c_reg;
        __syncthreads();
    }

    if (lane == 0) atomicMax(tmax_ws, firstBelow);
}

// ---------------------------------------------------------------------------
// SPLIT PATH, PHASE 1: the proven kernel truncated after the exp pass (every
// fp instruction byte-identical: rolled distance loop, LDS d-stash, same
// expressions), plus inert stores of s (coalesced column-major from LDS) and
// attn to workspace. No selections made here.
// ---------------------------------------------------------------------------
__global__ __launch_bounds__(64) void gat_sims_kernel(
    const float* __restrict__ mail,
    const float* __restrict__ attn_w,
    const float* __restrict__ src_norm,
    float* __restrict__ sims_g,
    float* __restrict__ attn_g)
{
    const int b = blockIdx.x;
    const int lane = threadIdx.x;

    __shared__ __align__(16) float sims[NN * 65];
    __shared__ float qarr[NN];
    __shared__ float sarr[NN];

    const float* __restrict__ myrow = mail + ((size_t)b * NN + lane) * FF;
    float a[FF];
#pragma unroll
    for (int k = 0; k < 8; ++k) {
        const float4 v = reinterpret_cast<const float4*>(myrow)[k];
        a[4*k+0] = v.x; a[4*k+1] = v.y; a[4*k+2] = v.z; a[4*k+3] = v.w;
    }
    const float sn = src_norm[b * NN + lane];

    float q0 = 0.f, q1 = 0.f, q2 = 0.f, q3 = 0.f;
#pragma unroll
    for (int k = 0; k < 8; ++k) {
        q0 = fmaf(a[4*k+0], a[4*k+0], q0);
        q1 = fmaf(a[4*k+1], a[4*k+1], q1);
        q2 = fmaf(a[4*k+2], a[4*k+2], q2);
        q3 = fmaf(a[4*k+3], a[4*k+3], q3);
    }
    const float q = (q0 + q1) + (q2 + q3);

    float lg = 0.f;
#pragma unroll
    for (int f = 0; f < FF; ++f) lg = fmaf(a[f], attn_w[f], lg);
    lg *= sn;

    qarr[lane] = q;
    sarr[lane] = sn;
    __syncthreads();

    float mx = lg;
#pragma unroll
    for (int off = 32; off > 0; off >>= 1)
        mx = fmaxf(mx, __shfl_xor(mx, off, 64));
    const float ex = __expf(lg - mx);
    float se = ex;
#pragma unroll
    for (int off = 32; off > 0; off >>= 1)
        se += __shfl_xor(se, off, 64);
    const float attn = ex / se;

    const float sqn = sn * sn * q;
    float dsum = 0.f;
    for (int m = 0; m < NN; ++m) {
        const float4* __restrict__ Am =
            reinterpret_cast<const float4*>(mail + ((size_t)b * NN + m) * FF);
        float g0 = 0.f, g1 = 0.f, g2 = 0.f, g3 = 0.f;
#pragma unroll
        for (int k = 0; k < 8; ++k) {
            const float4 v = Am[k];
            g0 = fmaf(a[4*k+0], v.x, g0);
            g1 = fmaf(a[4*k+1], v.y, g1);
            g2 = fmaf(a[4*k+2], v.z, g2);
            g3 = fmaf(a[4*k+3], v.w, g3);
        }
        const float g  = (g0 + g1) + (g2 + g3);
        const float sm = sarr[m];
        const float qm = qarr[m];
        const float sqm = sm * sm * qm;
        const float d2  = (sqn - 2.f * (sn * sm) * g) + sqm;
        const float d   = sqrtf(fmaxf(d2, 0.f));
        dsum += d;
        sims[lane * 65 + m] = d;
    }

    float tot = dsum;
#pragma unroll
    for (int off = 32; off > 0; off >>= 1)
        tot += __shfl_xor(tot, off, 64);
    const float meand = tot * (1.f / (float)(NN * NN));
    const float inv   = -1.f / meand;   // SIGMA = 1

#pragma unroll
    for (int m = 0; m < NN; ++m) {
        const float d = sims[lane * 65 + m];
        const float s = __expf(d * inv);
        sims[lane * 65 + m] = s;
    }

    attn_g[b * NN + lane] = attn;
    __syncthreads();   // all rows resident in LDS before cooperative write-out

    // coalesced column-major write-out: per m, lanes store 256 B contiguous
    float* __restrict__ simsb = sims_g + (size_t)b * NN * NN;
    for (int m = 0; m < NN; ++m)
        simsb[m * NN + lane] = sims[m * 65 + lane];
}

// ---------------------------------------------------------------------------
// SPLIT PATH, PHASE 2: the greedy loop verbatim. srow/attn come from phase-1
// bits in global memory (opaque to the compiler); the loop's fp ops (add /
// sub / max / single mul) have zero contraction freedom, so selections are a
// pure function of those bits == the proven kernel's selections.
// LDS = 256 B -> occupancy is VGPR-bound (~5 waves/SIMD vs 22% before).
// ---------------------------------------------------------------------------
__global__ __launch_bounds__(64) void gat_greedy2_kernel(
    const float* __restrict__ sims_g,
    const float* __restrict__ attn_g,
    int* __restrict__ tmax_ws,
    unsigned char* __restrict__ sels_ws)
{
    const int b = blockIdx.x;
    const int lane = threadIdx.x;

    __shared__ __align__(16) float c_lds[NN];

    const float* __restrict__ simsb = sims_g + (size_t)b * NN * NN;

    // own row -> registers (L3-resident; written by phase 1)
    float srow[NN];
    const float4* __restrict__ rp =
        reinterpret_cast<const float4*>(simsb + (size_t)lane * NN);
#pragma unroll
    for (int k = 0; k < 16; ++k) {
        const float4 v = rp[k];
        srow[4*k+0] = v.x; srow[4*k+1] = v.y;
        srow[4*k+2] = v.z; srow[4*k+3] = v.w;
    }
#pragma unroll
    for (int m = 0; m < NN; ++m)
        asm volatile("" : "+v"(srow[m]));

    const float attn = attn_g[b * NN + lane];

    c_lds[lane] = 0.f;
    float c_reg = 0.f;
    __syncthreads();

    int firstBelow = ITERS;
    bool seenBelow = false;

    for (int t = 0; t < ITERS; ++t) {
        float gain = 0.f;
#pragma unroll
        for (int k = 0; k < 16; ++k) {
            const float4 cv = reinterpret_cast<const float4*>(c_lds)[k];
            gain += fmaxf(srow[4*k+0] - cv.x, 0.f);
            gain += fmaxf(srow[4*k+1] - cv.y, 0.f);
            gain += fmaxf(srow[4*k+2] - cv.z, 0.f);
            gain += fmaxf(srow[4*k+3] - cv.w, 0.f);
        }
        gain *= attn;

        float gv = gain; int gi = lane;
#pragma unroll
        for (int off = 32; off > 0; off >>= 1) {
            const float ov = __shfl_xor(gv, off, 64);
            const int   oi = __shfl_xor(gi, off, 64);
            if (ov > gv || (ov == gv && oi < gi)) { gv = ov; gi = oi; }
        }

        if (!seenBelow && gv < THRESH) { firstBelow = t; seenBelow = true; }
        if (lane == 0) sels_ws[(size_t)b * ITERS + t] = (unsigned char)gi;

        // row gi column read from global (L3-warm, coalesced 256 B)
        const float srl = simsb[gi * NN + lane];
        c_reg = fmaxf(c_reg, srl);
        c_lds[lane] = c_reg;
        __syncthreads();
    }

    if (lane == 0) atomicMax(tmax_ws, firstBelow);
}

// ---------------------------------------------------------------------------
// ACCUM (proven r0 form)
// ---------------------------------------------------------------------------
__global__ __launch_bounds__(64) void gat_accum_kernel(
    const float* __restrict__ mail,
    const float* __restrict__ src_norm,
    const float* __restrict__ dst_norm,
    const int* __restrict__ tmax_ws,
    const unsigned char* __restrict__ sels_ws,
    float* __restrict__ out)
{
    const int lane = threadIdx.x & 31;
    const int b = blockIdx.x * 2 + (threadIdx.x >> 5);
    const int C = min(ITERS, *tmax_ws + 1);
    const unsigned char* __restrict__ sb = sels_ws + (size_t)b * ITERS;
    float acc = 0.f;
    for (int t = 0; t < C; ++t) {
        const int sel = sb[t];
        acc = fmaf(mail[((size_t)b * NN + sel) * FF + lane],
                   src_norm[b * NN + sel], acc);
    }
    out[b * FF + lane] = acc * dst_norm[b];
}

extern "C" void kernel_launch(void* const* d_in, const int* in_sizes, int n_in,
                              void* d_out, int out_size, void* d_ws, size_t ws_size,
                              hipStream_t stream)
{
    const float* mail     = (const float*)d_in[0];
    const float* attn_w   = (const float*)d_in[1];
    const float* src_norm = (const float*)d_in[2];
    const float* dst_norm = (const float*)d_in[3];
    float* out = (float*)d_out;

    int* tmax_ws = (int*)d_ws;
    unsigned char* sels_ws = (unsigned char*)d_ws + 16;

    hipMemsetAsync(d_ws, 0, 4, stream);   // zero the Tmax word

    if (ws_size >= WS_NEEDED) {
        float* attn_g = (float*)((char*)d_ws + ATTN_OFF);
        float* sims_g = (float*)((char*)d_ws + SIMS_OFF);
        gat_sims_kernel<<<dim3(B_TOT), dim3(64), 0, stream>>>(
            mail, attn_w, src_norm, sims_g, attn_g);
        gat_greedy2_kernel<<<dim3(B_TOT), dim3(64), 0, stream>>>(
            sims_g, attn_g, tmax_ws, sels_ws);
    } else {
        gat_greedy_kernel<<<dim3(B_TOT), dim3(64), 0, stream>>>(
            mail, attn_w, src_norm, tmax_ws, sels_ws);
    }
    gat_accum_kernel<<<dim3(B_TOT / 2), dim3(64), 0, stream>>>(
        mail, src_norm, dst_norm, tmax_ws, sels_ws, out);
}